// Round 1
// baseline (17348.621 us; speedup 1.0000x reference)
//
#include <hip/hip_runtime.h>
#include <hip/hip_bf16.h>
#include <stdint.h>

typedef short short8 __attribute__((ext_vector_type(8)));
typedef float f32x4 __attribute__((ext_vector_type(4)));
typedef unsigned short u16;

__device__ __forceinline__ float bf2f(u16 b){ unsigned u = ((unsigned)b) << 16; float f; __builtin_memcpy(&f, &u, 4); return f; }
__device__ __forceinline__ u16 f2bf(float f){ unsigned u; __builtin_memcpy(&u, &f, 4); u = (u + 0x7fffu + ((u >> 16) & 1u)) >> 16; return (u16)u; }
__device__ __forceinline__ float sigm(float x){ return 1.f / (1.f + __expf(-x)); }
__device__ __forceinline__ float tanh_(float x){ float e = __expf(2.f * x); return 1.f - 2.f / (e + 1.f); }

// ---------------- init: convert weights to bf16, init h(-1)=state0 into hbuf[1] ----------------
__global__ __launch_bounds__(256) void k_init(const float* __restrict__ Wih, const float* __restrict__ Whh,
                                              const float* __restrict__ Wly, const float* __restrict__ s0,
                                              u16* __restrict__ Wihb, u16* __restrict__ Whhb,
                                              u16* __restrict__ Wlyb, u16* __restrict__ hbuf)
{
  int i = blockIdx.x * 256 + threadIdx.x;
  int n = 3072 * 1024;
  for (int idx = i; idx < n; idx += gridDim.x * 256){
    Wihb[idx] = f2bf(Wih[idx]);
    Whhb[idx] = f2bf(Whh[idx]);
  }
  if (i < 32 * 1024) Wlyb[i] = f2bf(Wly[i]);
  if (i < 65536) hbuf[65536 + i] = f2bf(s0[i & 1023]);  // hbuf[1][g][b][k], state0 broadcast
}

// ---------------- xe = tanh(inputs @ W_e^T + b_e), stored bf16 [32768][1024] ----------------
__global__ __launch_bounds__(256) void k_xe(const float* __restrict__ inp, const float* __restrict__ We,
                                            const float* __restrict__ be, u16* __restrict__ xe)
{
  __shared__ float si[64][32];
  size_t m0 = (size_t)blockIdx.x * 64;
  int tid = threadIdx.x;
  for (int i = tid; i < 2048; i += 256)
    si[i >> 5][i & 31] = inp[m0 * 32 + i];
  __syncthreads();
  #pragma unroll
  for (int jj = 0; jj < 4; ++jj){
    int j = jj * 256 + tid;
    f32x4 wr[8];
    #pragma unroll
    for (int q = 0; q < 8; ++q)
      wr[q] = *(const f32x4*)(We + (size_t)j * 32 + q * 4);
    float bias = be[j];
    for (int mi = 0; mi < 64; ++mi){
      float acc = bias;
      #pragma unroll
      for (int q = 0; q < 8; ++q){
        f32x4 x = *(const f32x4*)(&si[mi][q * 4]);  // same addr all lanes -> LDS broadcast
        acc += x[0]*wr[q][0] + x[1]*wr[q][1] + x[2]*wr[q][2] + x[3]*wr[q][3];
      }
      xe[(m0 + mi) * 1024 + j] = f2bf(tanh_(acc));
    }
  }
}

// ---------------- xp = xe @ W_ih^T + b_ih, bf16 [32768][3072]; 128x128x32 MFMA tiles ----------------
__global__ __launch_bounds__(256) void k_xp(const u16* __restrict__ A, const u16* __restrict__ Bw,
                                            const float* __restrict__ bias, u16* __restrict__ C)
{
  __shared__ u16 As[128 * 32];
  __shared__ u16 Bs[128 * 32];
  int tid = threadIdx.x;
  int lane = tid & 63, wv = tid >> 6;
  int wr = wv >> 1, wc = wv & 1;
  int l15 = lane & 15, l4 = lane >> 4;
  int bid = blockIdx.x;
  int mb = bid / 24, nb = bid % 24;
  int m0 = mb * 128, n0 = nb * 128;

  int srow = tid >> 2;          // staging row 0..63 (+64 second pass)
  int sslot = tid & 3;          // 8-elem k slot
  // XOR swizzle: slot' = slot ^ ((row>>1)&3); involution, applied on write and read
  int wb0 = srow * 64 + ((sslot ^ ((srow >> 1) & 3)) * 16);
  int swz = (l15 >> 1) & 3;
  int rb_ = l15 * 64 + ((l4 ^ swz) * 16);

  f32x4 acc[4][4] = {};
  const u16* Aptr = A + (size_t)m0 * 1024;
  const u16* Bptr = Bw + (size_t)n0 * 1024;

  for (int k0 = 0; k0 < 1024; k0 += 32){
    short8 va0 = *(const short8*)(Aptr + (size_t)srow * 1024 + k0 + sslot * 8);
    short8 va1 = *(const short8*)(Aptr + (size_t)(srow + 64) * 1024 + k0 + sslot * 8);
    short8 vb0 = *(const short8*)(Bptr + (size_t)srow * 1024 + k0 + sslot * 8);
    short8 vb1 = *(const short8*)(Bptr + (size_t)(srow + 64) * 1024 + k0 + sslot * 8);
    __syncthreads();
    *(short8*)((char*)As + wb0)        = va0;
    *(short8*)((char*)As + wb0 + 4096) = va1;
    *(short8*)((char*)Bs + wb0)        = vb0;
    *(short8*)((char*)Bs + wb0 + 4096) = vb1;
    __syncthreads();
    short8 af[4], bf[4];
    #pragma unroll
    for (int i = 0; i < 4; ++i){
      af[i] = *(const short8*)((const char*)As + (wr * 64 + i * 16) * 64 + rb_);
      bf[i] = *(const short8*)((const char*)Bs + (wc * 64 + i * 16) * 64 + rb_);
    }
    #pragma unroll
    for (int i = 0; i < 4; ++i)
      #pragma unroll
      for (int j = 0; j < 4; ++j)
        acc[i][j] = __builtin_amdgcn_mfma_f32_16x16x32_bf16(af[i], bf[j], acc[i][j], 0, 0, 0);
  }
  #pragma unroll
  for (int j = 0; j < 4; ++j){
    int n = n0 + wc * 64 + j * 16 + l15;
    float bv = bias[n];
    #pragma unroll
    for (int i = 0; i < 4; ++i){
      int mrow = m0 + wr * 64 + i * 16 + l4 * 4;
      #pragma unroll
      for (int r = 0; r < 4; ++r)
        C[(size_t)(mrow + r) * 3072 + n] = f2bf(acc[i][j][r] + bv);
    }
  }
}

// ---------------- GRU recurrence: 4 groups x 16 batch; 64 WGs/group; weights VGPR-resident ----------------
// WG (g, s): owns h indices j in [s*16, s*16+16), all 3 gates (W_hh rows j, 1024+j, 2048+j).
// Waves K-split 1024 -> 4x256. Per step: all-gather h (bf16, double-buffered in global),
// 24 MFMA/wave, LDS reduce, wave0 gates + stores, atomic counter barrier per (group, step).
__global__ __launch_bounds__(256, 1) void k_rec(const u16* __restrict__ Whhb, const float* __restrict__ bhh,
                                                const u16* __restrict__ xpb, const float* __restrict__ s0,
                                                u16* __restrict__ hbuf, float* __restrict__ states,
                                                int* __restrict__ cnt)
{
  int w = blockIdx.x;
  int g = (w & 7) >> 1;                  // group 0..3 (XCD-pair heuristic placement)
  int s = ((w >> 3) << 1) | (w & 1);     // slice 0..63
  int jb = s * 16;
  int tid = threadIdx.x, lane = tid & 63, wv = tid >> 6;
  int l15 = lane & 15, l4 = lane >> 4;

  // persistent weights: B-fragments, lane l15 = row-within-16, l4*8 = k-subblock
  short8 wreg[3][8];
  #pragma unroll
  for (int gt = 0; gt < 3; ++gt){
    const u16* wp = Whhb + (size_t)(gt * 1024 + jb + l15) * 1024 + wv * 256 + l4 * 8;
    #pragma unroll
    for (int ks = 0; ks < 8; ++ks)
      wreg[gt][ks] = *(const short8*)(wp + ks * 32);
  }
  float bb0 = bhh[jb + l15], bb1 = bhh[1024 + jb + l15], bb2 = bhh[2048 + jb + l15];
  float hreg[4];
  { float v = s0[jb + l15]; hreg[0] = hreg[1] = hreg[2] = hreg[3] = v; }

  __shared__ f32x4 part[4][3][64];
  int* mycnt = cnt + g * 512;

  for (int t = 0; t < 512; ++t){
    // prefetch xp_t (wave0 only; independent of recurrence -> overlaps spin + MFMA)
    u16 xq[12];
    if (wv == 0){
      #pragma unroll
      for (int gt = 0; gt < 3; ++gt)
        #pragma unroll
        for (int r = 0; r < 4; ++r){
          int b = g * 16 + l4 * 4 + r;
          xq[gt * 4 + r] = xpb[((size_t)b * 512 + t) * 3072 + gt * 1024 + jb + l15];
        }
    }
    if (t > 0){
      const int* cp = mycnt + t - 1;
      while (__hip_atomic_load(cp, __ATOMIC_RELAXED, __HIP_MEMORY_SCOPE_AGENT) < 64)
        __builtin_amdgcn_s_sleep(1);
      __threadfence();                       // agent acquire: invalidate stale caches
      __builtin_amdgcn_sched_barrier(0);
    }
    int rbuf = (t & 1) ^ 1;
    const u16* hsrc = hbuf + ((size_t)(rbuf * 4 + g) * 16 + l15) * 1024 + wv * 256 + l4 * 8;
    short8 af[8];
    #pragma unroll
    for (int ks = 0; ks < 8; ++ks)
      af[ks] = *(const short8*)(hsrc + ks * 32);
    f32x4 a0 = {}, a1 = {}, a2 = {};
    #pragma unroll
    for (int ks = 0; ks < 8; ++ks){
      a0 = __builtin_amdgcn_mfma_f32_16x16x32_bf16(af[ks], wreg[0][ks], a0, 0, 0, 0);
      a1 = __builtin_amdgcn_mfma_f32_16x16x32_bf16(af[ks], wreg[1][ks], a1, 0, 0, 0);
      a2 = __builtin_amdgcn_mfma_f32_16x16x32_bf16(af[ks], wreg[2][ks], a2, 0, 0, 0);
    }
    part[wv][0][lane] = a0;
    part[wv][1][lane] = a1;
    part[wv][2][lane] = a2;
    __syncthreads();
    // waves 1-3 race ahead to t+1; their next partial writes are gated by cnt[t]==64,
    // which requires our wave0's add below (which happens after it reads part[]) -> safe.
    if (wv == 0){
      f32x4 g0 = part[0][0][lane] + part[1][0][lane] + part[2][0][lane] + part[3][0][lane];
      f32x4 g1 = part[0][1][lane] + part[1][1][lane] + part[2][1][lane] + part[3][1][lane];
      f32x4 g2 = part[0][2][lane] + part[1][2][lane] + part[2][2][lane] + part[3][2][lane];
      int wb = t & 1;
      #pragma unroll
      for (int r = 0; r < 4; ++r){
        float rr = sigm(bf2f(xq[r])     + g0[r] + bb0);
        float zz = sigm(bf2f(xq[4 + r]) + g1[r] + bb1);
        float nn = tanh_(bf2f(xq[8 + r]) + rr * (g2[r] + bb2));
        float hn = (1.f - zz) * nn + zz * hreg[r];
        hreg[r] = hn;
        int b = g * 16 + l4 * 4 + r;
        states[((size_t)b * 512 + t) * 1024 + jb + l15] = hn;
        hbuf[((size_t)(wb * 4 + g) * 16 + (l4 * 4 + r)) * 1024 + jb + l15] = f2bf(hn);
      }
      __threadfence();                       // agent release: push h to coherence point
      if (lane == 0)
        __hip_atomic_fetch_add(mycnt + t, 1, __ATOMIC_RELEASE, __HIP_MEMORY_SCOPE_AGENT);
    }
  }
}

// ---------------- outputs = states @ W_ly^T ----------------
__global__ __launch_bounds__(256) void k_out(const float* __restrict__ st, const u16* __restrict__ Wlyb,
                                             float* __restrict__ out)
{
  int tid = threadIdx.x, lane = tid & 63, wv = tid >> 6;
  int l15 = lane & 15, l4 = lane >> 4;
  size_t m0 = (size_t)blockIdx.x * 256;
  f32x4 acc[4][2] = {};
  for (int kc = 0; kc < 4; ++kc){
    short8 bfr[2][8];
    #pragma unroll
    for (int nt = 0; nt < 2; ++nt){
      const u16* bp = Wlyb + (size_t)(nt * 16 + l15) * 1024 + kc * 256 + l4 * 8;
      #pragma unroll
      for (int ks = 0; ks < 8; ++ks)
        bfr[nt][ks] = *(const short8*)(bp + ks * 32);
    }
    #pragma unroll
    for (int mt = 0; mt < 4; ++mt){
      const float* sp = st + (m0 + wv * 64 + mt * 16 + l15) * 1024 + kc * 256 + l4 * 8;
      #pragma unroll
      for (int ks = 0; ks < 8; ++ks){
        f32x4 p0 = *(const f32x4*)(sp + ks * 32);
        f32x4 p1 = *(const f32x4*)(sp + ks * 32 + 4);
        short8 a;
        a[0] = (short)f2bf(p0[0]); a[1] = (short)f2bf(p0[1]); a[2] = (short)f2bf(p0[2]); a[3] = (short)f2bf(p0[3]);
        a[4] = (short)f2bf(p1[0]); a[5] = (short)f2bf(p1[1]); a[6] = (short)f2bf(p1[2]); a[7] = (short)f2bf(p1[3]);
        acc[mt][0] = __builtin_amdgcn_mfma_f32_16x16x32_bf16(a, bfr[0][ks], acc[mt][0], 0, 0, 0);
        acc[mt][1] = __builtin_amdgcn_mfma_f32_16x16x32_bf16(a, bfr[1][ks], acc[mt][1], 0, 0, 0);
      }
    }
  }
  #pragma unroll
  for (int mt = 0; mt < 4; ++mt)
    #pragma unroll
    for (int nt = 0; nt < 2; ++nt)
      #pragma unroll
      for (int r = 0; r < 4; ++r)
        out[(m0 + wv * 64 + mt * 16 + l4 * 4 + r) * 32 + nt * 16 + l15] = acc[mt][nt][r];
}

extern "C" void kernel_launch(void* const* d_in, const int* in_sizes, int n_in,
                              void* d_out, int out_size, void* d_ws, size_t ws_size,
                              hipStream_t stream)
{
  const float* inputs = (const float*)d_in[0];
  const float* s0     = (const float*)d_in[1];
  const float* We     = (const float*)d_in[2];
  const float* be     = (const float*)d_in[3];
  const float* Wih    = (const float*)d_in[4];
  const float* bih    = (const float*)d_in[5];
  const float* Whh    = (const float*)d_in[6];
  const float* bhh    = (const float*)d_in[7];
  const float* Wly    = (const float*)d_in[8];

  float* out    = (float*)d_out;                 // (B,T,32)
  float* states = out + (size_t)64 * 512 * 32;   // (B,T,1024)

  char* ws = (char*)d_ws;
  u16* xe   = (u16*)ws;  ws += (size_t)32768 * 1024 * 2;   // 67 MB
  u16* xpb  = (u16*)ws;  ws += (size_t)32768 * 3072 * 2;   // 201 MB
  u16* Wihb = (u16*)ws;  ws += (size_t)3072 * 1024 * 2;
  u16* Whhb = (u16*)ws;  ws += (size_t)3072 * 1024 * 2;
  u16* Wlyb = (u16*)ws;  ws += (size_t)32 * 1024 * 2;
  u16* hbuf = (u16*)ws;  ws += (size_t)2 * 4 * 16 * 1024 * 2;
  int* cnt  = (int*)ws;  ws += (size_t)4 * 512 * 4;

  hipMemsetAsync(cnt, 0, 4 * 512 * 4, stream);
  k_init<<<dim3(4096), dim3(256), 0, stream>>>(Wih, Whh, Wly, s0, Wihb, Whhb, Wlyb, hbuf);
  k_xe<<<dim3(512), dim3(256), 0, stream>>>(inputs, We, be, xe);
  k_xp<<<dim3(6144), dim3(256), 0, stream>>>(xe, Wihb, bih, xpb);

  void* args[] = { (void*)&Whhb, (void*)&bhh, (void*)&xpb, (void*)&s0, (void*)&hbuf, (void*)&states, (void*)&cnt };
  hipError_t e = hipLaunchCooperativeKernel((const void*)k_rec, dim3(256), dim3(256), args, 0, stream);
  if (e != hipSuccess){
    (void)hipGetLastError();
    k_rec<<<dim3(256), dim3(256), 0, stream>>>(Whhb, bhh, xpb, s0, hbuf, states, cnt);
  }
  k_out<<<dim3(128), dim3(256), 0, stream>>>(states, Wlyb, out);
}

// Round 2
// 6399.352 us; speedup vs baseline: 2.7110x; 2.7110x over previous
//
#include <hip/hip_runtime.h>
#include <hip/hip_bf16.h>
#include <stdint.h>

typedef short short8 __attribute__((ext_vector_type(8)));
typedef float f32x4 __attribute__((ext_vector_type(4)));
typedef unsigned short u16;

__device__ __forceinline__ float bf2f(u16 b){ unsigned u = ((unsigned)b) << 16; float f; __builtin_memcpy(&f, &u, 4); return f; }
__device__ __forceinline__ u16 f2bf(float f){ unsigned u; __builtin_memcpy(&u, &f, 4); u = (u + 0x7fffu + ((u >> 16) & 1u)) >> 16; return (u16)u; }
__device__ __forceinline__ float sigm(float x){ return 1.f / (1.f + __expf(-x)); }
__device__ __forceinline__ float tanh_(float x){ float e = __expf(2.f * x); return 1.f - 2.f / (e + 1.f); }

// coherent (device-visible) accesses: sc0 sc1 bypass L1 and operate at the device
// coherence point -- no cache-invalidating fences needed anywhere.
__device__ __forceinline__ short8 ld_cohx4(const u16* p){
  short8 d;
  asm volatile("global_load_dwordx4 %0, %1, off sc0 sc1" : "=v"(d) : "v"(p) : "memory");
  return d;
}
__device__ __forceinline__ int ld_coh_u32(const int* p){
  int d;
  asm volatile("global_load_dword %0, %1, off sc0 sc1" : "=v"(d) : "v"(p) : "memory");
  return d;
}
__device__ __forceinline__ void st_coh_u16(u16* p, u16 v){
  asm volatile("global_store_short %0, %1, off sc0 sc1" :: "v"(p), "v"(v) : "memory");
}
__device__ __forceinline__ void st_coh_u32(int* p, int v){
  asm volatile("global_store_dword %0, %1, off sc0 sc1" :: "v"(p), "v"(v) : "memory");
}
__device__ __forceinline__ void wait_vm0(){ asm volatile("s_waitcnt vmcnt(0)" ::: "memory"); }

// ---------------- init: convert weights to bf16, zero flags, init h(-1)=state0 ----------------
__global__ __launch_bounds__(256) void k_init(const float* __restrict__ Wih, const float* __restrict__ Whh,
                                              const float* __restrict__ Wly, const float* __restrict__ s0,
                                              u16* __restrict__ Wihb, u16* __restrict__ Whhb,
                                              u16* __restrict__ Wlyb, u16* __restrict__ hbuf,
                                              int* __restrict__ flags)
{
  int i = blockIdx.x * 256 + threadIdx.x;
  int n = 3072 * 1024;
  for (int idx = i; idx < n; idx += gridDim.x * 256){
    Wihb[idx] = f2bf(Wih[idx]);
    Whhb[idx] = f2bf(Whh[idx]);
  }
  if (i < 32 * 1024) Wlyb[i] = f2bf(Wly[i]);
  if (i < 65536) hbuf[65536 + i] = f2bf(s0[i & 1023]);  // hbuf[buf=1][64 rows][1024], state0 broadcast
  if (i < 8 * 512 * 64) flags[i] = 0;                   // per-launch re-zero (graph replay safe)
}

// ---------------- xe = tanh(inputs @ W_e^T + b_e), stored bf16 [32768][1024] ----------------
__global__ __launch_bounds__(256) void k_xe(const float* __restrict__ inp, const float* __restrict__ We,
                                            const float* __restrict__ be, u16* __restrict__ xe)
{
  __shared__ float si[64][32];
  size_t m0 = (size_t)blockIdx.x * 64;
  int tid = threadIdx.x;
  for (int i = tid; i < 2048; i += 256)
    si[i >> 5][i & 31] = inp[m0 * 32 + i];
  __syncthreads();
  #pragma unroll
  for (int jj = 0; jj < 4; ++jj){
    int j = jj * 256 + tid;
    f32x4 wr[8];
    #pragma unroll
    for (int q = 0; q < 8; ++q)
      wr[q] = *(const f32x4*)(We + (size_t)j * 32 + q * 4);
    float bias = be[j];
    for (int mi = 0; mi < 64; ++mi){
      float acc = bias;
      #pragma unroll
      for (int q = 0; q < 8; ++q){
        f32x4 x = *(const f32x4*)(&si[mi][q * 4]);
        acc += x[0]*wr[q][0] + x[1]*wr[q][1] + x[2]*wr[q][2] + x[3]*wr[q][3];
      }
      xe[(m0 + mi) * 1024 + j] = f2bf(tanh_(acc));
    }
  }
}

// ---------------- xp = xe @ W_ih^T + b_ih, bf16 [32768][3072]; 128x128x32 MFMA tiles ----------------
__global__ __launch_bounds__(256) void k_xp(const u16* __restrict__ A, const u16* __restrict__ Bw,
                                            const float* __restrict__ bias, u16* __restrict__ C)
{
  __shared__ u16 As[128 * 32];
  __shared__ u16 Bs[128 * 32];
  int tid = threadIdx.x;
  int lane = tid & 63, wv = tid >> 6;
  int wr = wv >> 1, wc = wv & 1;
  int l15 = lane & 15, l4 = lane >> 4;
  int bid = blockIdx.x;
  int mb = bid / 24, nb = bid % 24;
  int m0 = mb * 128, n0 = nb * 128;

  int srow = tid >> 2;
  int sslot = tid & 3;
  int wb0 = srow * 64 + ((sslot ^ ((srow >> 1) & 3)) * 16);
  int swz = (l15 >> 1) & 3;
  int rb_ = l15 * 64 + ((l4 ^ swz) * 16);

  f32x4 acc[4][4] = {};
  const u16* Aptr = A + (size_t)m0 * 1024;
  const u16* Bptr = Bw + (size_t)n0 * 1024;

  for (int k0 = 0; k0 < 1024; k0 += 32){
    short8 va0 = *(const short8*)(Aptr + (size_t)srow * 1024 + k0 + sslot * 8);
    short8 va1 = *(const short8*)(Aptr + (size_t)(srow + 64) * 1024 + k0 + sslot * 8);
    short8 vb0 = *(const short8*)(Bptr + (size_t)srow * 1024 + k0 + sslot * 8);
    short8 vb1 = *(const short8*)(Bptr + (size_t)(srow + 64) * 1024 + k0 + sslot * 8);
    __syncthreads();
    *(short8*)((char*)As + wb0)        = va0;
    *(short8*)((char*)As + wb0 + 4096) = va1;
    *(short8*)((char*)Bs + wb0)        = vb0;
    *(short8*)((char*)Bs + wb0 + 4096) = vb1;
    __syncthreads();
    short8 af[4], bf[4];
    #pragma unroll
    for (int i = 0; i < 4; ++i){
      af[i] = *(const short8*)((const char*)As + (wr * 64 + i * 16) * 64 + rb_);
      bf[i] = *(const short8*)((const char*)Bs + (wc * 64 + i * 16) * 64 + rb_);
    }
    #pragma unroll
    for (int i = 0; i < 4; ++i)
      #pragma unroll
      for (int j = 0; j < 4; ++j)
        acc[i][j] = __builtin_amdgcn_mfma_f32_16x16x32_bf16(af[i], bf[j], acc[i][j], 0, 0, 0);
  }
  #pragma unroll
  for (int j = 0; j < 4; ++j){
    int n = n0 + wc * 64 + j * 16 + l15;
    float bv = bias[n];
    #pragma unroll
    for (int i = 0; i < 4; ++i){
      int mrow = m0 + wr * 64 + i * 16 + l4 * 4;
      #pragma unroll
      for (int r = 0; r < 4; ++r)
        C[(size_t)(mrow + r) * 3072 + n] = f2bf(acc[i][j][r] + bv);
    }
  }
}

// ---------------- GRU recurrence: 8 groups x 8 batch; 64 WGs/group (1 XCD/group heuristic) ----------------
// WG (g,s): owns h cols [s*16, s*16+16) for all 3 gates; weights VGPR-resident (96 VGPR/lane).
// Sync: per-(group,step,slice) flag array, sc0sc1 write-through stores + read-only polling.
// No threadfence / cache invalidation anywhere in the loop.
__global__ __launch_bounds__(256, 2) void k_rec(const u16* __restrict__ Whhb, const float* __restrict__ bhh,
                                                const u16* __restrict__ xpb, const float* __restrict__ s0,
                                                u16* __restrict__ hbuf, float* __restrict__ states,
                                                int* __restrict__ flags)
{
  int w = blockIdx.x;
  int g = w & 7;                 // group -> XCD (round-robin heuristic; correctness placement-free)
  int s = w >> 3;                // slice 0..63
  int jb = s * 16;
  int tid = threadIdx.x, lane = tid & 63, wv = tid >> 6;
  int l15 = lane & 15, l4 = lane >> 4;

  // persistent W_hh fragments: lane l15 = out-col-within-16, wave wv owns K [wv*256, wv*256+256)
  short8 wreg[3][8];
  #pragma unroll
  for (int gt = 0; gt < 3; ++gt){
    const u16* wp = Whhb + (size_t)(gt * 1024 + jb + l15) * 1024 + wv * 256 + l4 * 8;
    #pragma unroll
    for (int ks = 0; ks < 8; ++ks)
      wreg[gt][ks] = *(const short8*)(wp + ks * 32);
  }
  float bb0 = bhh[jb + l15], bb1 = bhh[1024 + jb + l15], bb2 = bhh[2048 + jb + l15];
  float hreg[4];
  { float v = s0[jb + l15]; hreg[0] = hreg[1] = hreg[2] = hreg[3] = v; }

  __shared__ f32x4 part[3][3][64];           // waves 1..3 partials
  int* fgrp = flags + (size_t)g * 512 * 64;

  for (int t = 0; t < 512; ++t){
    // xp_t prefetch (wave0 only; rows via (l4&1) so all lanes load valid addrs)
    u16 xq[12];
    if (wv == 0){
      #pragma unroll
      for (int gt = 0; gt < 3; ++gt)
        #pragma unroll
        for (int r = 0; r < 4; ++r){
          int b = g * 8 + (l4 & 1) * 4 + r;
          xq[gt * 4 + r] = xpb[((size_t)b * 512 + t) * 3072 + gt * 1024 + jb + l15];
        }
    }
    if (t > 0){
      const int* fp_ = fgrp + (size_t)(t - 1) * 64 + lane;   // lane i polls slice i's flag
      while (true){
        int v = ld_coh_u32(fp_);
        wait_vm0();
        if (__all(v != 0)) break;
        __builtin_amdgcn_s_sleep(1);
      }
      __builtin_amdgcn_sched_barrier(0);
    }
    int rbuf = (t & 1) ^ 1;
    const u16* hsrc = hbuf + ((size_t)rbuf * 64 + g * 8 + (l15 & 7)) * 1024 + wv * 256 + l4 * 8;
    short8 af[8];
    #pragma unroll
    for (int ks = 0; ks < 8; ++ks)
      af[ks] = ld_cohx4(hsrc + ks * 32);
    wait_vm0();
    __builtin_amdgcn_sched_barrier(0);
    f32x4 a0 = {}, a1 = {}, a2 = {};
    #pragma unroll
    for (int ks = 0; ks < 8; ++ks){
      a0 = __builtin_amdgcn_mfma_f32_16x16x32_bf16(af[ks], wreg[0][ks], a0, 0, 0, 0);
      a1 = __builtin_amdgcn_mfma_f32_16x16x32_bf16(af[ks], wreg[1][ks], a1, 0, 0, 0);
      a2 = __builtin_amdgcn_mfma_f32_16x16x32_bf16(af[ks], wreg[2][ks], a2, 0, 0, 0);
    }
    if (wv){
      part[wv - 1][0][lane] = a0;
      part[wv - 1][1][lane] = a1;
      part[wv - 1][2][lane] = a2;
    }
    __syncthreads();
    // waves 1-3 race to t+1; their next part[] writes are gated by flag[t] (set only after
    // our wave0 reads part[] below) -> no WAR hazard, barrier instances stay matched.
    if (wv == 0){
      f32x4 g0 = a0 + part[0][0][lane] + part[1][0][lane] + part[2][0][lane];
      f32x4 g1 = a1 + part[0][1][lane] + part[1][1][lane] + part[2][1][lane];
      f32x4 g2 = a2 + part[0][2][lane] + part[1][2][lane] + part[2][2][lane];
      int wb = t & 1;
      float hn_[4];
      #pragma unroll
      for (int r = 0; r < 4; ++r){
        float rr = sigm(bf2f(xq[r])      + g0[r] + bb0);
        float zz = sigm(bf2f(xq[4 + r])  + g1[r] + bb1);
        float nn = tanh_(bf2f(xq[8 + r]) + rr * (g2[r] + bb2));
        hn_[r] = (1.f - zz) * nn + zz * hreg[r];
        hreg[r] = hn_[r];
      }
      if (l4 < 2){
        #pragma unroll
        for (int r = 0; r < 4; ++r){
          int row = l4 * 4 + r;
          st_coh_u16(hbuf + ((size_t)wb * 64 + g * 8 + row) * 1024 + jb + l15, f2bf(hn_[r]));
        }
      }
      wait_vm0();                                        // h at coherence point before flag
      if (lane == 0)
        st_coh_u32(fgrp + (size_t)t * 64 + s, 1);
      if (l4 < 2){
        #pragma unroll
        for (int r = 0; r < 4; ++r)
          states[((size_t)(g * 8 + l4 * 4 + r) * 512 + t) * 1024 + jb + l15] = hn_[r];
      }
    }
  }
}

// ---------------- outputs = states @ W_ly^T ----------------
__global__ __launch_bounds__(256) void k_out(const float* __restrict__ st, const u16* __restrict__ Wlyb,
                                             float* __restrict__ out)
{
  int tid = threadIdx.x, lane = tid & 63, wv = tid >> 6;
  int l15 = lane & 15, l4 = lane >> 4;
  size_t m0 = (size_t)blockIdx.x * 256;
  f32x4 acc[4][2] = {};
  for (int kc = 0; kc < 4; ++kc){
    short8 bfr[2][8];
    #pragma unroll
    for (int nt = 0; nt < 2; ++nt){
      const u16* bp = Wlyb + (size_t)(nt * 16 + l15) * 1024 + kc * 256 + l4 * 8;
      #pragma unroll
      for (int ks = 0; ks < 8; ++ks)
        bfr[nt][ks] = *(const short8*)(bp + ks * 32);
    }
    #pragma unroll
    for (int mt = 0; mt < 4; ++mt){
      const float* sp = st + (m0 + wv * 64 + mt * 16 + l15) * 1024 + kc * 256 + l4 * 8;
      #pragma unroll
      for (int ks = 0; ks < 8; ++ks){
        f32x4 p0 = *(const f32x4*)(sp + ks * 32);
        f32x4 p1 = *(const f32x4*)(sp + ks * 32 + 4);
        short8 a;
        a[0] = (short)f2bf(p0[0]); a[1] = (short)f2bf(p0[1]); a[2] = (short)f2bf(p0[2]); a[3] = (short)f2bf(p0[3]);
        a[4] = (short)f2bf(p1[0]); a[5] = (short)f2bf(p1[1]); a[6] = (short)f2bf(p1[2]); a[7] = (short)f2bf(p1[3]);
        acc[mt][0] = __builtin_amdgcn_mfma_f32_16x16x32_bf16(a, bfr[0][ks], acc[mt][0], 0, 0, 0);
        acc[mt][1] = __builtin_amdgcn_mfma_f32_16x16x32_bf16(a, bfr[1][ks], acc[mt][1], 0, 0, 0);
      }
    }
  }
  #pragma unroll
  for (int mt = 0; mt < 4; ++mt)
    #pragma unroll
    for (int nt = 0; nt < 2; ++nt)
      #pragma unroll
      for (int r = 0; r < 4; ++r)
        out[(m0 + wv * 64 + mt * 16 + l4 * 4 + r) * 32 + nt * 16 + l15] = acc[mt][nt][r];
}

extern "C" void kernel_launch(void* const* d_in, const int* in_sizes, int n_in,
                              void* d_out, int out_size, void* d_ws, size_t ws_size,
                              hipStream_t stream)
{
  const float* inputs = (const float*)d_in[0];
  const float* s0     = (const float*)d_in[1];
  const float* We     = (const float*)d_in[2];
  const float* be     = (const float*)d_in[3];
  const float* Wih    = (const float*)d_in[4];
  const float* bih    = (const float*)d_in[5];
  const float* Whh    = (const float*)d_in[6];
  const float* bhh    = (const float*)d_in[7];
  const float* Wly    = (const float*)d_in[8];

  float* out    = (float*)d_out;                 // (B,T,32)
  float* states = out + (size_t)64 * 512 * 32;   // (B,T,1024)

  char* ws = (char*)d_ws;
  u16* xe   = (u16*)ws;  ws += (size_t)32768 * 1024 * 2;
  u16* xpb  = (u16*)ws;  ws += (size_t)32768 * 3072 * 2;
  u16* Wihb = (u16*)ws;  ws += (size_t)3072 * 1024 * 2;
  u16* Whhb = (u16*)ws;  ws += (size_t)3072 * 1024 * 2;
  u16* Wlyb = (u16*)ws;  ws += (size_t)32 * 1024 * 2;
  u16* hbuf = (u16*)ws;  ws += (size_t)2 * 64 * 1024 * 2;  // [buf][64 rows][1024] bf16
  int* flags= (int*)ws;  ws += (size_t)8 * 512 * 64 * 4;   // [group][t][slice]

  k_init<<<dim3(4096), dim3(256), 0, stream>>>(Wih, Whh, Wly, s0, Wihb, Whhb, Wlyb, hbuf, flags);
  k_xe<<<dim3(512), dim3(256), 0, stream>>>(inputs, We, be, xe);
  k_xp<<<dim3(6144), dim3(256), 0, stream>>>(xe, Wihb, bih, xpb);

  void* args[] = { (void*)&Whhb, (void*)&bhh, (void*)&xpb, (void*)&s0, (void*)&hbuf, (void*)&states, (void*)&flags };
  hipError_t e = hipLaunchCooperativeKernel((const void*)k_rec, dim3(512), dim3(256), args, 0, stream);
  if (e != hipSuccess){
    (void)hipGetLastError();
    k_rec<<<dim3(512), dim3(256), 0, stream>>>(Whhb, bhh, xpb, s0, hbuf, states, flags);
  }
  k_out<<<dim3(128), dim3(256), 0, stream>>>(states, Wlyb, out);
}

// Round 3
// 3239.251 us; speedup vs baseline: 5.3558x; 1.9756x over previous
//
#include <hip/hip_runtime.h>
#include <hip/hip_bf16.h>
#include <stdint.h>

typedef short short8 __attribute__((ext_vector_type(8)));
typedef float f32x4 __attribute__((ext_vector_type(4)));
typedef unsigned short u16;

__device__ __forceinline__ float bf2f(u16 b){ unsigned u = ((unsigned)b) << 16; float f; __builtin_memcpy(&f, &u, 4); return f; }
__device__ __forceinline__ u16 f2bf(float f){ unsigned u; __builtin_memcpy(&u, &f, 4); u = (u + 0x7fffu + ((u >> 16) & 1u)) >> 16; return (u16)u; }
__device__ __forceinline__ float sigm(float x){ return 1.f / (1.f + __expf(-x)); }
__device__ __forceinline__ float tanh_(float x){ float e = __expf(2.f * x); return 1.f - 2.f / (e + 1.f); }

// coherent (device-visible) accesses: sc0 sc1 bypass L1/L2 and hit the device
// coherence point -- no cache-invalidating fences anywhere.
__device__ __forceinline__ short8 ld_cohx4(const u16* p){
  short8 d;
  asm volatile("global_load_dwordx4 %0, %1, off sc0 sc1" : "=v"(d) : "v"(p) : "memory");
  return d;
}
__device__ __forceinline__ int ld_coh_u32(const int* p){
  int d;
  asm volatile("global_load_dword %0, %1, off sc0 sc1" : "=v"(d) : "v"(p) : "memory");
  return d;
}
__device__ __forceinline__ void st_coh_u16(u16* p, u16 v){
  asm volatile("global_store_short %0, %1, off sc0 sc1" :: "v"(p), "v"(v) : "memory");
}
__device__ __forceinline__ void st_coh_u32(int* p, int v){
  asm volatile("global_store_dword %0, %1, off sc0 sc1" :: "v"(p), "v"(v) : "memory");
}
__device__ __forceinline__ void wait_vm0(){ asm volatile("s_waitcnt vmcnt(0)" ::: "memory"); }

// ---------------- init: bf16 weights, zero flags, h(-1)=state0 into slab buf 1 ----------------
// hslab layout: [buf(2)][g(4)][slice(64)][row(16)][col(16)] bf16  (512B per slice)
__global__ __launch_bounds__(256) void k_init(const float* __restrict__ Wih, const float* __restrict__ Whh,
                                              const float* __restrict__ Wly, const float* __restrict__ s0,
                                              u16* __restrict__ Wihb, u16* __restrict__ Whhb,
                                              u16* __restrict__ Wlyb, u16* __restrict__ hslab,
                                              int* __restrict__ flags)
{
  int i = blockIdx.x * 256 + threadIdx.x;
  int n = 3072 * 1024;
  for (int idx = i; idx < n; idx += gridDim.x * 256){
    Wihb[idx] = f2bf(Wih[idx]);
    Whhb[idx] = f2bf(Whh[idx]);
  }
  if (i < 32 * 1024) Wlyb[i] = f2bf(Wly[i]);
  if (i < 65536){
    int k = ((i >> 8) & 63) * 16 + (i & 15);   // slice*16 + col
    hslab[65536 + i] = f2bf(s0[k]);
  }
  if (i < 4 * 512 * 64) flags[i] = 0;          // per-launch re-zero (graph replay safe)
}

// ---------------- xe = tanh(inputs @ W_e^T + b_e), stored bf16 [32768][1024] ----------------
__global__ __launch_bounds__(256) void k_xe(const float* __restrict__ inp, const float* __restrict__ We,
                                            const float* __restrict__ be, u16* __restrict__ xe)
{
  __shared__ float si[64][32];
  size_t m0 = (size_t)blockIdx.x * 64;
  int tid = threadIdx.x;
  for (int i = tid; i < 2048; i += 256)
    si[i >> 5][i & 31] = inp[m0 * 32 + i];
  __syncthreads();
  #pragma unroll
  for (int jj = 0; jj < 4; ++jj){
    int j = jj * 256 + tid;
    f32x4 wr[8];
    #pragma unroll
    for (int q = 0; q < 8; ++q)
      wr[q] = *(const f32x4*)(We + (size_t)j * 32 + q * 4);
    float bias = be[j];
    for (int mi = 0; mi < 64; ++mi){
      float acc = bias;
      #pragma unroll
      for (int q = 0; q < 8; ++q){
        f32x4 x = *(const f32x4*)(&si[mi][q * 4]);
        acc += x[0]*wr[q][0] + x[1]*wr[q][1] + x[2]*wr[q][2] + x[3]*wr[q][3];
      }
      xe[(m0 + mi) * 1024 + j] = f2bf(tanh_(acc));
    }
  }
}

// ---------------- xp = xe @ W_ih^T + b_ih, bf16 [32768][3072]; 128x128x32 MFMA tiles ----------------
__global__ __launch_bounds__(256) void k_xp(const u16* __restrict__ A, const u16* __restrict__ Bw,
                                            const float* __restrict__ bias, u16* __restrict__ C)
{
  __shared__ u16 As[128 * 32];
  __shared__ u16 Bs[128 * 32];
  int tid = threadIdx.x;
  int lane = tid & 63, wv = tid >> 6;
  int wr = wv >> 1, wc = wv & 1;
  int l15 = lane & 15, l4 = lane >> 4;
  int bid = blockIdx.x;
  int mb = bid / 24, nb = bid % 24;
  int m0 = mb * 128, n0 = nb * 128;

  int srow = tid >> 2;
  int sslot = tid & 3;
  int wb0 = srow * 64 + ((sslot ^ ((srow >> 1) & 3)) * 16);
  int swz = (l15 >> 1) & 3;
  int rb_ = l15 * 64 + ((l4 ^ swz) * 16);

  f32x4 acc[4][4] = {};
  const u16* Aptr = A + (size_t)m0 * 1024;
  const u16* Bptr = Bw + (size_t)n0 * 1024;

  for (int k0 = 0; k0 < 1024; k0 += 32){
    short8 va0 = *(const short8*)(Aptr + (size_t)srow * 1024 + k0 + sslot * 8);
    short8 va1 = *(const short8*)(Aptr + (size_t)(srow + 64) * 1024 + k0 + sslot * 8);
    short8 vb0 = *(const short8*)(Bptr + (size_t)srow * 1024 + k0 + sslot * 8);
    short8 vb1 = *(const short8*)(Bptr + (size_t)(srow + 64) * 1024 + k0 + sslot * 8);
    __syncthreads();
    *(short8*)((char*)As + wb0)        = va0;
    *(short8*)((char*)As + wb0 + 4096) = va1;
    *(short8*)((char*)Bs + wb0)        = vb0;
    *(short8*)((char*)Bs + wb0 + 4096) = vb1;
    __syncthreads();
    short8 af[4], bf[4];
    #pragma unroll
    for (int i = 0; i < 4; ++i){
      af[i] = *(const short8*)((const char*)As + (wr * 64 + i * 16) * 64 + rb_);
      bf[i] = *(const short8*)((const char*)Bs + (wc * 64 + i * 16) * 64 + rb_);
    }
    #pragma unroll
    for (int i = 0; i < 4; ++i)
      #pragma unroll
      for (int j = 0; j < 4; ++j)
        acc[i][j] = __builtin_amdgcn_mfma_f32_16x16x32_bf16(af[i], bf[j], acc[i][j], 0, 0, 0);
  }
  #pragma unroll
  for (int j = 0; j < 4; ++j){
    int n = n0 + wc * 64 + j * 16 + l15;
    float bv = bias[n];
    #pragma unroll
    for (int i = 0; i < 4; ++i){
      int mrow = m0 + wr * 64 + i * 16 + l4 * 4;
      #pragma unroll
      for (int r = 0; r < 4; ++r)
        C[(size_t)(mrow + r) * 3072 + n] = f2bf(acc[i][j][r] + bv);
    }
  }
}

// ---------------- GRU recurrence: 4 groups x 16 batch; 64 WGs/group; 1 WG/CU ----------------
// WG (g,s): owns h cols [s*16,s*16+16) for 3 gates; W_hh fragments VGPR-resident (96 VGPR).
// h exchange slice-major (512B/slice): producer stores 8 lines, consumer A-frag loads are
// fully-coalesced 1KB/instr. Each wave polls ONLY its own 16 source slices.
__global__ __launch_bounds__(256, 1) void k_rec(const u16* __restrict__ Whhb, const float* __restrict__ bhh,
                                                const u16* __restrict__ xpb, const float* __restrict__ s0,
                                                u16* __restrict__ hslab, float* __restrict__ states,
                                                int* __restrict__ flags)
{
  int w = blockIdx.x;
  int g = w & 3;                 // group
  int s = w >> 2;                // slice 0..63
  int jb = s * 16;
  int tid = threadIdx.x, lane = tid & 63, wv = tid >> 6;
  int l15 = lane & 15, l4 = lane >> 4;

  // persistent W_hh fragments: lane l15 = out-col-within-16, wave wv owns K [wv*256, +256)
  short8 wreg[3][8];
  #pragma unroll
  for (int gt = 0; gt < 3; ++gt){
    const u16* wp = Whhb + (size_t)(gt * 1024 + jb + l15) * 1024 + wv * 256 + l4 * 8;
    #pragma unroll
    for (int ks = 0; ks < 8; ++ks)
      wreg[gt][ks] = *(const short8*)(wp + ks * 32);
  }
  float bb0 = bhh[jb + l15], bb1 = bhh[1024 + jb + l15], bb2 = bhh[2048 + jb + l15];
  float hreg[4];
  { float v = s0[jb + l15]; hreg[0] = hreg[1] = hreg[2] = hreg[3] = v; }

  __shared__ f32x4 part[3][3][64];           // waves 1..3 partials

  for (int t = 0; t < 512; ++t){
    // xp_t prefetch (wave0; issued before poll so latency hides under the spin)
    u16 xq[12];
    if (wv == 0){
      #pragma unroll
      for (int gt = 0; gt < 3; ++gt)
        #pragma unroll
        for (int r = 0; r < 4; ++r){
          int b = g * 16 + l4 * 4 + r;
          xq[gt * 4 + r] = xpb[((size_t)b * 512 + t) * 3072 + gt * 1024 + jb + l15];
        }
    }
    if (t > 0){
      // poll only the 16 slices this wave consumes (lanes duplicate across l4 -> 1-line txn)
      const int* fp_ = flags + ((size_t)g * 512 + (t - 1)) * 64 + wv * 16 + l15;
      while (true){
        int v = ld_coh_u32(fp_);
        wait_vm0();
        if (__all(v != 0)) break;
        __builtin_amdgcn_s_sleep(1);
      }
      __builtin_amdgcn_sched_barrier(0);
    }
    // A-fragment loads, fully coalesced from slice-major slab
    int rbuf = (t & 1) ^ 1;
    const char* hs = (const char*)hslab + (((size_t)rbuf * 4 + g) * 64 + wv * 16) * 512;
    const char* hl = hs + l15 * 32 + (l4 & 1) * 16;
    short8 af[8];
    #pragma unroll
    for (int ks = 0; ks < 8; ++ks)
      af[ks] = ld_cohx4((const u16*)(hl + (ks * 2 + (l4 >> 1)) * 512));
    wait_vm0();
    __builtin_amdgcn_sched_barrier(0);
    f32x4 a0 = {}, a1 = {}, a2 = {};
    #pragma unroll
    for (int ks = 0; ks < 8; ++ks){
      a0 = __builtin_amdgcn_mfma_f32_16x16x32_bf16(af[ks], wreg[0][ks], a0, 0, 0, 0);
      a1 = __builtin_amdgcn_mfma_f32_16x16x32_bf16(af[ks], wreg[1][ks], a1, 0, 0, 0);
      a2 = __builtin_amdgcn_mfma_f32_16x16x32_bf16(af[ks], wreg[2][ks], a2, 0, 0, 0);
    }
    if (wv){
      part[wv - 1][0][lane] = a0;
      part[wv - 1][1][lane] = a1;
      part[wv - 1][2][lane] = a2;
    }
    __syncthreads();
    // waves 1-3 race to t+1; their next part[] writes are gated by flag[t][own s], set only
    // after our wave0 reads part[] below -> no WAR hazard, barriers stay matched.
    if (wv == 0){
      f32x4 g0 = a0 + part[0][0][lane] + part[1][0][lane] + part[2][0][lane];
      f32x4 g1 = a1 + part[0][1][lane] + part[1][1][lane] + part[2][1][lane];
      f32x4 g2 = a2 + part[0][2][lane] + part[1][2][lane] + part[2][2][lane];
      int wb = t & 1;
      float hn_[4];
      #pragma unroll
      for (int r = 0; r < 4; ++r){
        float rr = sigm(bf2f(xq[r])      + g0[r] + bb0);
        float zz = sigm(bf2f(xq[4 + r])  + g1[r] + bb1);
        float nn = tanh_(bf2f(xq[8 + r]) + rr * (g2[r] + bb2));
        hn_[r] = (1.f - zz) * nn + zz * hreg[r];
        hreg[r] = hn_[r];
      }
      // store own 16x16 h-slice, slice-major (contiguous 512B block)
      u16* hw = hslab + (((size_t)wb * 4 + g) * 64 + s) * 256;
      #pragma unroll
      for (int r = 0; r < 4; ++r)
        st_coh_u16(hw + (l4 * 4 + r) * 16 + l15, f2bf(hn_[r]));
      wait_vm0();                                        // h at coherence point before flag
      if (lane == 0)
        st_coh_u32(flags + ((size_t)g * 512 + t) * 64 + s, 1);
      #pragma unroll
      for (int r = 0; r < 4; ++r)
        states[((size_t)(g * 16 + l4 * 4 + r) * 512 + t) * 1024 + jb + l15] = hn_[r];
    }
  }
}

// ---------------- outputs = states @ W_ly^T ----------------
__global__ __launch_bounds__(256) void k_out(const float* __restrict__ st, const u16* __restrict__ Wlyb,
                                             float* __restrict__ out)
{
  int tid = threadIdx.x, lane = tid & 63, wv = tid >> 6;
  int l15 = lane & 15, l4 = lane >> 4;
  size_t m0 = (size_t)blockIdx.x * 256;
  f32x4 acc[4][2] = {};
  for (int kc = 0; kc < 4; ++kc){
    short8 bfr[2][8];
    #pragma unroll
    for (int nt = 0; nt < 2; ++nt){
      const u16* bp = Wlyb + (size_t)(nt * 16 + l15) * 1024 + kc * 256 + l4 * 8;
      #pragma unroll
      for (int ks = 0; ks < 8; ++ks)
        bfr[nt][ks] = *(const short8*)(bp + ks * 32);
    }
    #pragma unroll
    for (int mt = 0; mt < 4; ++mt){
      const float* sp = st + (m0 + wv * 64 + mt * 16 + l15) * 1024 + kc * 256 + l4 * 8;
      #pragma unroll
      for (int ks = 0; ks < 8; ++ks){
        f32x4 p0 = *(const f32x4*)(sp + ks * 32);
        f32x4 p1 = *(const f32x4*)(sp + ks * 32 + 4);
        short8 a;
        a[0] = (short)f2bf(p0[0]); a[1] = (short)f2bf(p0[1]); a[2] = (short)f2bf(p0[2]); a[3] = (short)f2bf(p0[3]);
        a[4] = (short)f2bf(p1[0]); a[5] = (short)f2bf(p1[1]); a[6] = (short)f2bf(p1[2]); a[7] = (short)f2bf(p1[3]);
        acc[mt][0] = __builtin_amdgcn_mfma_f32_16x16x32_bf16(a, bfr[0][ks], acc[mt][0], 0, 0, 0);
        acc[mt][1] = __builtin_amdgcn_mfma_f32_16x16x32_bf16(a, bfr[1][ks], acc[mt][1], 0, 0, 0);
      }
    }
  }
  #pragma unroll
  for (int mt = 0; mt < 4; ++mt)
    #pragma unroll
    for (int nt = 0; nt < 2; ++nt)
      #pragma unroll
      for (int r = 0; r < 4; ++r)
        out[(m0 + wv * 64 + mt * 16 + l4 * 4 + r) * 32 + nt * 16 + l15] = acc[mt][nt][r];
}

extern "C" void kernel_launch(void* const* d_in, const int* in_sizes, int n_in,
                              void* d_out, int out_size, void* d_ws, size_t ws_size,
                              hipStream_t stream)
{
  const float* inputs = (const float*)d_in[0];
  const float* s0     = (const float*)d_in[1];
  const float* We     = (const float*)d_in[2];
  const float* be     = (const float*)d_in[3];
  const float* Wih    = (const float*)d_in[4];
  const float* bih    = (const float*)d_in[5];
  const float* Whh    = (const float*)d_in[6];
  const float* bhh    = (const float*)d_in[7];
  const float* Wly    = (const float*)d_in[8];

  float* out    = (float*)d_out;                 // (B,T,32)
  float* states = out + (size_t)64 * 512 * 32;   // (B,T,1024)

  char* ws = (char*)d_ws;
  u16* xe   = (u16*)ws;  ws += (size_t)32768 * 1024 * 2;
  u16* xpb  = (u16*)ws;  ws += (size_t)32768 * 3072 * 2;
  u16* Wihb = (u16*)ws;  ws += (size_t)3072 * 1024 * 2;
  u16* Whhb = (u16*)ws;  ws += (size_t)3072 * 1024 * 2;
  u16* Wlyb = (u16*)ws;  ws += (size_t)32 * 1024 * 2;
  u16* hslab= (u16*)ws;  ws += (size_t)2 * 4 * 64 * 256 * 2;  // [buf][g][slice][16][16] bf16
  int* flags= (int*)ws;  ws += (size_t)4 * 512 * 64 * 4;      // [g][t][slice]

  k_init<<<dim3(4096), dim3(256), 0, stream>>>(Wih, Whh, Wly, s0, Wihb, Whhb, Wlyb, hslab, flags);
  k_xe<<<dim3(512), dim3(256), 0, stream>>>(inputs, We, be, xe);
  k_xp<<<dim3(6144), dim3(256), 0, stream>>>(xe, Wihb, bih, xpb);

  void* args[] = { (void*)&Whhb, (void*)&bhh, (void*)&xpb, (void*)&s0, (void*)&hslab, (void*)&states, (void*)&flags };
  hipError_t e = hipLaunchCooperativeKernel((const void*)k_rec, dim3(256), dim3(256), args, 0, stream);
  if (e != hipSuccess){
    (void)hipGetLastError();
    k_rec<<<dim3(256), dim3(256), 0, stream>>>(Whhb, bhh, xpb, s0, hslab, states, flags);
  }
  k_out<<<dim3(128), dim3(256), 0, stream>>>(states, Wlyb, out);
}